// Round 11
// baseline (122.094 us; speedup 1.0000x reference)
//
#include <hip/hip_runtime.h>
#include <hip/hip_bf16.h>
#include <math.h>

// Problem constants (fixed by setup_inputs): B=8, N=2048, C=128, TOP_K=512
// Algebraic structure (verified passing since R1):
//  - adj = softmax(relu(GL GL^T)) + I > 0 everywhere  => att == e, GL unused.
//  - e[b,i,j] = leaky_relu(p_i + q_j) monotone in p_i => mask depends only on
//    (b,i): row kept iff (p_i, -i) >= 512th largest (p, -idx).
//  - Unselected rows: softmax(all-zeros) = uniform => relu(mean_j h[b,j,:]).
//  - Kept rows: exp(leaky_relu(p+q)) separates at q >= -p into e^p e^q and
//    e^{.01p} e^{.01q}; sort by q => suffix/prefix sums + bsearch per row.
//
// R1: k_mean 252us -> 2-stage. R2: k_rank 52.8us -> p-sort threshold.
// R3: u64-key sort + fused scans; 119.9. R4: REGRESSED 131 (gemm 512thr;
// k_out 108KB LDS). R5: REGRESSED 130.7 (k_prep serial launch). R6:
// REGRESSED 155.8 (per-block __threadfence = L2 writeback on multi-XCD;
// never per-block device fences). R7: R3 restore 120.2. R8: k_tab flatten
// + concurrent mean: 116.5. R9: gemm 4x8/thread + CL=64 tables-in-k_out,
// 4 launches: 111.2.
// R10: sort swapped to 256thr x 8elem register bitonic (3 LDS phases vs 10,
//      j<=4 in-register, j=8..256 shfl; scan 256-wide w/ 8-elem sub-scans).
//      Critical-path latency cut; verified-correct variant from R5/R6.

#define B_ 8
#define N_ 2048
#define C_ 128
#define TOPK_ 512
#define NCH_ 32      // chunks per batch
#define CL_ 64       // chunk length (NCH_*CL_ == N_)
#define NP1_ 2052    // padded N+1 stride (mult of 4 -> float4-aligned rows)

// ---------------- ws layout (floats) ----------------
#define H_OFF    ((size_t)0)
#define P_OFF    (H_OFF + (size_t)B_*N_*C_)
#define Q_OFF    (P_OFF + (size_t)B_*N_)
#define QS_OFF   (Q_OFF + (size_t)B_*N_)
#define US_OFF   (QS_OFF + (size_t)B_*N_)
#define VS_OFF   (US_OFF + (size_t)B_*N_)
#define SRT_OFF  (VS_OFF + (size_t)B_*N_)          // ints
#define SUS_OFF  (SRT_OFF + (size_t)B_*N_)         // B*NP1_
#define PVS_OFF  (SUS_OFF + (size_t)B_*NP1_)       // B*NP1_
#define SUL_OFF  (PVS_OFF + (size_t)B_*NP1_)
#define PVL_OFF  (SUL_OFF + (size_t)B_*N_*128)
#define TOTU_OFF (PVL_OFF + (size_t)B_*N_*128)
#define TOTV_OFF (TOTU_OFF + (size_t)B_*NCH_*128)
#define MR_OFF   (TOTV_OFF + (size_t)B_*NCH_*128)
#define MPART_OFF (MR_OFF + (size_t)B_*C_)         // B*32*128 tile col sums
#define PTHR_OFF (MPART_OFF + (size_t)B_*32*C_)    // B floats
#define ITHR_OFF (PTHR_OFF + (size_t)B_)           // B ints

// monotone float <-> sortable uint
__device__ __forceinline__ unsigned enc_f(float f) {
  unsigned b = __float_as_uint(f);
  return b ^ ((b >> 31) ? 0xFFFFFFFFu : 0x80000000u);
}
__device__ __forceinline__ float dec_f(unsigned e) {
  unsigned b = (e & 0x80000000u) ? (e ^ 0x80000000u) : ~e;
  return __uint_as_float(b);
}
__device__ __forceinline__ unsigned long long sxor64(unsigned long long v, int m) {
  int lo = __shfl_xor((int)(unsigned)(v & 0xffffffffULL), m, 64);
  int hi = __shfl_xor((int)(unsigned)(v >> 32), m, 64);
  return (((unsigned long long)(unsigned)hi) << 32) | (unsigned)lo;
}
#define CSWAP(A, Bx, ASC) do { \
  bool sw_ = (ASC) ? ((A) > (Bx)) : ((A) < (Bx)); \
  if (sw_) { unsigned long long tm_ = (A); (A) = (Bx); (Bx) = tm_; } \
} while (0)

// ---------------- K1: h = x@W (f32), p = h@a1, q = h@a2, mean partials ------
// 256 threads, 64 rows/block. Thread (cg=t&15, rp=t>>4) owns rows
// {4rp..4rp+3} x cols {4cg..4cg+3, 4cg+64..4cg+67}: 32 FMA per k-iter from
// 2 ds_read_b128 (W) + 4 ds_read_b32 (x) -> VALU-bound. <=2-way bank alias.
__global__ __launch_bounds__(256) void k_gemm(const float* __restrict__ x,
                                              const float* __restrict__ W,
                                              const float* __restrict__ a,
                                              float* __restrict__ h,
                                              float* __restrict__ p,
                                              float* __restrict__ q,
                                              float* __restrict__ mpart) {
  __shared__ float Wl[64 * 128];       // 32 KB
  __shared__ float xl[64 * 68];        // 17 KB (reused as 16x128 scratch)
  __shared__ float a1l[128], a2l[128];
  __shared__ float redp[64][16], redq[64][16];  // 8 KB
  const int t = threadIdx.x;
  const int r0 = blockIdx.x * 64;
  if (t < 128) { a1l[t] = a[t]; a2l[t] = a[128 + t]; }
  const int cg = t & 15, rp = t >> 4;
  float acc[4][8];
#pragma unroll
  for (int r = 0; r < 4; ++r)
#pragma unroll
    for (int j = 0; j < 8; ++j) acc[r][j] = 0.f;

  for (int kc = 0; kc < 2; ++kc) {
    __syncthreads();
    const float4* W4 = (const float4*)(W + (size_t)kc * 64 * 128);
    float4* Wl4 = (float4*)Wl;
#pragma unroll
    for (int i = 0; i < 8; ++i) Wl4[t + 256 * i] = W4[t + 256 * i];
#pragma unroll
    for (int i = 0; i < 4; ++i) {
      int idx = t + 256 * i;
      int row = idx >> 4, c4i = idx & 15;
      float4 v = *(const float4*)(x + (size_t)(r0 + row) * 128 + kc * 64 + c4i * 4);
      ((float4*)xl)[row * 17 + c4i] = v;
    }
    __syncthreads();
    for (int k = 0; k < 64; ++k) {
      const float4* Wr = (const float4*)(Wl + k * 128);
      float4 w0 = Wr[cg];
      float4 w1 = Wr[cg + 16];
#pragma unroll
      for (int r = 0; r < 4; ++r) {
        float xv = xl[(4 * rp + r) * 68 + k];
        acc[r][0] = fmaf(xv, w0.x, acc[r][0]);
        acc[r][1] = fmaf(xv, w0.y, acc[r][1]);
        acc[r][2] = fmaf(xv, w0.z, acc[r][2]);
        acc[r][3] = fmaf(xv, w0.w, acc[r][3]);
        acc[r][4] = fmaf(xv, w1.x, acc[r][4]);
        acc[r][5] = fmaf(xv, w1.y, acc[r][5]);
        acc[r][6] = fmaf(xv, w1.z, acc[r][6]);
        acc[r][7] = fmaf(xv, w1.w, acc[r][7]);
      }
    }
  }
  // epilogue: h stores + p/q partials + mean column partials
  const int c0 = 4 * cg, c1 = 4 * cg + 64;
  size_t hb = (size_t)r0 * 128;
  __syncthreads();               // xl reads done before scratch reuse
  float* scratch = xl;           // 16 x 128 four-row sums
#pragma unroll
  for (int r = 0; r < 4; ++r) {
    int row = 4 * rp + r;
    *(float4*)(h + hb + (size_t)row * 128 + c0) =
        make_float4(acc[r][0], acc[r][1], acc[r][2], acc[r][3]);
    *(float4*)(h + hb + (size_t)row * 128 + c1) =
        make_float4(acc[r][4], acc[r][5], acc[r][6], acc[r][7]);
    float pp = 0.f, qq = 0.f;
#pragma unroll
    for (int j = 0; j < 4; ++j) {
      pp = fmaf(acc[r][j], a1l[c0 + j], pp);
      qq = fmaf(acc[r][j], a2l[c0 + j], qq);
      pp = fmaf(acc[r][4 + j], a1l[c1 + j], pp);
      qq = fmaf(acc[r][4 + j], a2l[c1 + j], qq);
    }
    redp[row][cg] = pp; redq[row][cg] = qq;
  }
#pragma unroll
  for (int j = 0; j < 4; ++j) {
    scratch[rp * 128 + c0 + j] = acc[0][j] + acc[1][j] + acc[2][j] + acc[3][j];
    scratch[rp * 128 + c1 + j] = acc[0][4+j] + acc[1][4+j] + acc[2][4+j] + acc[3][4+j];
  }
  __syncthreads();
  if (t < 64) {
    float sp = 0.f, sq = 0.f;
#pragma unroll
    for (int i = 0; i < 16; ++i) { sp += redp[t][i]; sq += redq[t][i]; }
    p[r0 + t] = sp;
    q[r0 + t] = sq;
  }
  if (t < 128) {
    float s = 0.f;
#pragma unroll
    for (int rr = 0; rr < 16; ++rr) s += scratch[rr * 128 + t];
    mpart[(size_t)blockIdx.x * 128 + t] = s;
  }
}

// ---------------- K2: 256thr x 8elem register bitonic sorts + mean ----------
// blocks 0..B_-1   : sort q[b] asc -> q_s/u_s/v_s/srt + SUS/PVS scans
// blocks B_..2B_-1 : sort p[b] desc -> pthr/ithr (rank-511 threshold)
// blocks 2B_..3B_-1: mrw[b] = relu(mean h cols) from mpart
__global__ __launch_bounds__(256) void k_sort(const float* __restrict__ q,
                                              const float* __restrict__ p,
                                              const float* __restrict__ mpart,
                                              float* __restrict__ q_s,
                                              float* __restrict__ u_s,
                                              float* __restrict__ v_s,
                                              int* __restrict__ srt,
                                              float* __restrict__ SUS,
                                              float* __restrict__ PVS,
                                              float* __restrict__ pthr,
                                              int* __restrict__ ithr,
                                              float* __restrict__ mrw) {
  __shared__ unsigned long long shS[N_];    // 16 KB
  __shared__ float2 sa[256], sb[256];       // 4 KB
  __shared__ float red[2][128];             // 1 KB (mean blocks)
  const int t = threadIdx.x;
  const int sblk = blockIdx.x;

  if (sblk >= 2 * B_) {
    // ---- mean path ----
    const int b = sblk - 2 * B_;
    const int c = t & 127, hlf = t >> 7;
    float s = 0.f;
#pragma unroll
    for (int j = 16 * hlf; j < 16 * hlf + 16; ++j)
      s += mpart[(size_t)(b * 32 + j) * 128 + c];
    red[hlf][c] = s;
    __syncthreads();
    if (t < 128)
      mrw[b * 128 + t] = fmaxf((red[0][t] + red[1][t]) * (1.0f / (float)N_), 0.f);
    return;
  }

  const bool isP = sblk >= B_;
  const int b = isP ? sblk - B_ : sblk;
  const float* src = isP ? p : q;
  unsigned long long r[8];
  {
    float4 f0 = *(const float4*)(src + b * N_ + 8 * t);
    float4 f1 = *(const float4*)(src + b * N_ + 8 * t + 4);
    float vs[8] = {f0.x, f0.y, f0.z, f0.w, f1.x, f1.y, f1.z, f1.w};
#pragma unroll
    for (int s = 0; s < 8; ++s) {
      unsigned kk = enc_f(vs[s]);
      if (isP) kk = ~kk;
      r[s] = (((unsigned long long)kk) << 32) | (unsigned)(8 * t + s);
    }
  }
  // k=2
  CSWAP(r[0], r[1], true);  CSWAP(r[2], r[3], false);
  CSWAP(r[4], r[5], true);  CSWAP(r[6], r[7], false);
  // k=4
  CSWAP(r[0], r[2], true);  CSWAP(r[1], r[3], true);
  CSWAP(r[4], r[6], false); CSWAP(r[5], r[7], false);
  CSWAP(r[0], r[1], true);  CSWAP(r[2], r[3], true);
  CSWAP(r[4], r[5], false); CSWAP(r[6], r[7], false);
  // k=8
  {
    const bool u8 = ((t & 1) == 0);
    CSWAP(r[0], r[4], u8); CSWAP(r[1], r[5], u8);
    CSWAP(r[2], r[6], u8); CSWAP(r[3], r[7], u8);
    CSWAP(r[0], r[2], u8); CSWAP(r[1], r[3], u8);
    CSWAP(r[4], r[6], u8); CSWAP(r[5], r[7], u8);
    CSWAP(r[0], r[1], u8); CSWAP(r[2], r[3], u8);
    CSWAP(r[4], r[5], u8); CSWAP(r[6], r[7], u8);
  }
  // k = 16 .. 2048
  for (int k = 16; k <= N_; k <<= 1) {
    const bool up = ((t & (k >> 3)) == 0);
    for (int j = k >> 1; j >= 8; j >>= 1) {
      const int m = j >> 3;
      const bool lower = ((t & m) == 0);
      const bool kmin = (up == lower);
      if (m >= 64) {                 // cross-wave: LDS
        __syncthreads();
#pragma unroll
        for (int s = 0; s < 8; s += 2)
          *(ulonglong2*)(shS + 8 * t + s) = make_ulonglong2(r[s], r[s + 1]);
        __syncthreads();
        const int pt = t ^ m;
#pragma unroll
        for (int s = 0; s < 8; ++s) {
          unsigned long long pv = shS[8 * pt + s];
          r[s] = kmin ? (r[s] < pv ? r[s] : pv) : (r[s] > pv ? r[s] : pv);
        }
      } else {                       // within-wave shuffle
#pragma unroll
        for (int s = 0; s < 8; ++s) {
          unsigned long long pv = sxor64(r[s], m);
          r[s] = kmin ? (r[s] < pv ? r[s] : pv) : (r[s] > pv ? r[s] : pv);
        }
      }
    }
    CSWAP(r[0], r[4], up); CSWAP(r[1], r[5], up);
    CSWAP(r[2], r[6], up); CSWAP(r[3], r[7], up);
    CSWAP(r[0], r[2], up); CSWAP(r[1], r[3], up);
    CSWAP(r[4], r[6], up); CSWAP(r[5], r[7], up);
    CSWAP(r[0], r[1], up); CSWAP(r[2], r[3], up);
    CSWAP(r[4], r[5], up); CSWAP(r[6], r[7], up);
  }

  if (isP) {
    if (t == 63) {   // element 511 = 8*63+7
      unsigned key = (unsigned)(r[7] >> 32);
      pthr[b] = dec_f(~key);
      ithr[b] = (int)(unsigned)(r[7] & 0xffffffffULL);
    }
    return;
  }
  // q path: outputs + fused scalar scans
  float vd[8], ud[8], wd[8];
  int idxs[8];
#pragma unroll
  for (int s = 0; s < 8; ++s) {
    vd[s] = dec_f((unsigned)(r[s] >> 32));
    idxs[s] = (int)(unsigned)(r[s] & 0xffffffffULL);
    ud[s] = __expf(vd[s]);
    wd[s] = __expf(0.01f * vd[s]);
  }
  const int eb = b * N_ + 8 * t;
  *(float4*)(q_s + eb)     = make_float4(vd[0], vd[1], vd[2], vd[3]);
  *(float4*)(q_s + eb + 4) = make_float4(vd[4], vd[5], vd[6], vd[7]);
  *(float4*)(u_s + eb)     = make_float4(ud[0], ud[1], ud[2], ud[3]);
  *(float4*)(u_s + eb + 4) = make_float4(ud[4], ud[5], ud[6], ud[7]);
  *(float4*)(v_s + eb)     = make_float4(wd[0], wd[1], wd[2], wd[3]);
  *(float4*)(v_s + eb + 4) = make_float4(wd[4], wd[5], wd[6], wd[7]);
  *(int4*)(srt + eb)       = make_int4(idxs[0], idxs[1], idxs[2], idxs[3]);
  *(int4*)(srt + eb + 4)   = make_int4(idxs[4], idxs[5], idxs[6], idxs[7]);
  float pu = 0.f, pw = 0.f;
#pragma unroll
  for (int s = 0; s < 8; ++s) { pu += ud[s]; pw += wd[s]; }
  sa[t] = make_float2(pu, pw);
  __syncthreads();
  float2* cur = sa; float2* nxt = sb;
  for (int off = 1; off < 256; off <<= 1) {
    float2 vv = cur[t];
    if (t >= off) { float2 o = cur[t - off]; vv.x += o.x; vv.y += o.y; }
    nxt[t] = vv;
    __syncthreads();
    float2* tmp = cur; cur = nxt; nxt = tmp;
  }
  const float Pu = cur[t].x, Pw = cur[t].y;
  const float total_u = cur[255].x;
  const float SUFt = total_u - (Pu - pu);   // suffix incl from element 8t
  const float PWex = Pw - pw;               // excl prefix before element 8t
  float outS[8], outP[8];
  float ru = 0.f, rw = 0.f;
#pragma unroll
  for (int s = 0; s < 8; ++s) {
    outS[s] = SUFt - ru;  ru += ud[s];
    outP[s] = PWex + rw;  rw += wd[s];
  }
  const size_t sbase = (size_t)b * NP1_ + 8 * t;
  *(float4*)(SUS + sbase)     = make_float4(outS[0], outS[1], outS[2], outS[3]);
  *(float4*)(SUS + sbase + 4) = make_float4(outS[4], outS[5], outS[6], outS[7]);
  *(float4*)(PVS + sbase)     = make_float4(outP[0], outP[1], outP[2], outP[3]);
  *(float4*)(PVS + sbase + 4) = make_float4(outP[4], outP[5], outP[6], outP[7]);
  if (t == 255) {
    SUS[(size_t)b * NP1_ + N_] = 0.f;
    PVS[(size_t)b * NP1_ + N_] = Pw;   // total_w
  }
}

// ---------------- K3: chunk-local suffix(u*h) / exclusive-prefix(w*h) --------
// 1 chunk of CL_=64 per 256-thread block (grid B*32 = 256 = full machine).
// Directions split: t<128 suffix scan (col t), t>=128 prefix scan (col t-128).
__global__ __launch_bounds__(256) void k_scanA(const float* __restrict__ h,
                                               const float* __restrict__ u_s,
                                               const float* __restrict__ v_s,
                                               const int* __restrict__ srt,
                                               float* __restrict__ SUl,
                                               float* __restrict__ PVl,
                                               float* __restrict__ totU,
                                               float* __restrict__ totV) {
  __shared__ float hl[CL_][128];   // 32 KB
  __shared__ float ul[CL_], vl[CL_];
  __shared__ int sl[CL_];
  const int b = blockIdx.x >> 5, ch = blockIdx.x & 31;
  const int t = threadIdx.x;
  const int base = b * N_ + ch * CL_;
  if (t < CL_) { ul[t] = u_s[base + t]; vl[t] = v_s[base + t]; sl[t] = srt[base + t]; }
  __syncthreads();
  // float4 gather: lane (c4 = t&31, rr = t>>5 in [0,8)) loads rows rr+8i
  {
    const int c4 = t & 31, rr = t >> 5;
#pragma unroll
    for (int i = 0; i < 8; ++i) {
      int tt = rr + 8 * i;
      float4 v = *(const float4*)(h + ((size_t)b * N_ + sl[tt]) * 128 + 4 * c4);
      *(float4*)(&hl[tt][4 * c4]) = v;
    }
  }
  __syncthreads();
  if (t < 128) {
    const int c = t;
    float run = 0.f;
    for (int tt = CL_ - 1; tt >= 0; --tt) {
      run = fmaf(ul[tt], hl[tt][c], run);
      SUl[((size_t)(base + tt)) * 128 + c] = run;
    }
    totU[(size_t)(b * NCH_ + ch) * 128 + c] = run;
  } else {
    const int c = t - 128;
    float run2 = 0.f;
    for (int tt = 0; tt < CL_; ++tt) {
      PVl[((size_t)(base + tt)) * 128 + c] = run2;
      run2 = fmaf(vl[tt], hl[tt][c], run2);
    }
    totV[(size_t)(b * NCH_ + ch) * 128 + c] = run2;
  }
}

// ---------------- K4: tables from totU/totV (LDS) + combine + store ---------
// Tables are 33x128x2 = 34 KB (NCH_=32) -> total ~76 KB LDS, 2 blocks/CU.
__global__ __launch_bounds__(256) void k_out(const float* __restrict__ p,
                                             const float* __restrict__ q_s,
                                             const float* __restrict__ pthr,
                                             const int* __restrict__ ithr,
                                             const float* __restrict__ SUS,
                                             const float* __restrict__ PVS,
                                             const float* __restrict__ SUl,
                                             const float* __restrict__ PVl,
                                             const float* __restrict__ totU,
                                             const float* __restrict__ totV,
                                             const float* __restrict__ mrw,
                                             float* __restrict__ out) {
  __shared__ float qs_l[N_];                 // 8 KB
  __shared__ float res[64 * 129];            // 33 KB
  __shared__ float CSUs[(NCH_ + 1) * 128];   // 16.9 KB
  __shared__ float CPVs[(NCH_ + 1) * 128];   // 16.9 KB
  __shared__ float mr[128];
  __shared__ float A_s[64], B_s[64], invD[64];
  __shared__ int lo_s[64], keep_s[64];
  const int b = blockIdx.x >> 5, tile = blockIdx.x & 31;
  const int t = threadIdx.x;
  const int i0 = tile * 64;
  for (int i = t; i < N_; i += 256) qs_l[i] = q_s[b * N_ + i];
  if (t < 128) {
    mr[t] = mrw[b * 128 + t];
    float s = 0.f;
    CSUs[NCH_ * 128 + t] = 0.f;
    for (int cc = NCH_ - 1; cc >= 0; --cc) {
      s += totU[(size_t)(b * NCH_ + cc) * 128 + t];
      CSUs[cc * 128 + t] = s;
    }
  } else {
    const int c2 = t - 128;
    float s2 = 0.f;
    for (int cc = 0; cc < NCH_; ++cc) {
      CPVs[cc * 128 + c2] = s2;
      s2 += totV[(size_t)(b * NCH_ + cc) * 128 + c2];
    }
    CPVs[NCH_ * 128 + c2] = s2;
  }
  __syncthreads();
  if (t < 64) {  // parallel bsearch + per-row scalars
    float pv = p[b * N_ + i0 + t];
    float thrv = pthr[b]; int thri = ithr[b];
    bool keep = (pv > thrv) || (pv == thrv && (i0 + t) <= thri);
    keep_s[t] = keep ? 1 : 0;
    float thr = -pv;
    int lo = 0, hi = N_;
    while (lo < hi) { int mid = (lo + hi) >> 1; if (qs_l[mid] < thr) lo = mid + 1; else hi = mid; }
    lo_s[t] = lo;
    float A = __expf(pv), Bv = __expf(0.01f * pv);
    A_s[t] = A; B_s[t] = Bv;
    float sus = SUS[(size_t)b * NP1_ + lo];
    float pvs = PVS[(size_t)b * NP1_ + lo];
    invD[t] = 1.0f / fmaf(A, sus, Bv * pvs);
  }
  __syncthreads();
  const int half = t >> 7, c = t & 127;
#pragma unroll 4
  for (int ii2 = 0; ii2 < 64; ii2 += 2) {
    int ii = ii2 + half;
    float outv;
    if (keep_s[ii]) {
      int lo = lo_s[ii];
      float A = A_s[ii], Bv = B_s[ii];
      float suc, pvc;
      if (lo < N_) {
        int chn = lo >> 6;   // / CL_
        size_t ro = ((size_t)(b * N_ + lo)) * 128;
        suc = SUl[ro + c] + CSUs[(chn + 1) * 128 + c];
        pvc = PVl[ro + c] + CPVs[chn * 128 + c];
      } else {
        suc = 0.f;
        pvc = CPVs[NCH_ * 128 + c];
      }
      outv = fmaxf(fmaf(A, suc, Bv * pvc) * invD[ii], 0.f);
    } else {
      outv = mr[c];
    }
    res[ii * 129 + c] = outv;
  }
  __syncthreads();
  // out[b][c][i] = res[i - i0][c]
#pragma unroll
  for (int pass = 0; pass < 8; ++pass) {
    int cc = (t >> 4) + pass * 16;
    int ii4 = (t & 15) * 4;
    float4 v;
    v.x = res[(ii4 + 0) * 129 + cc];
    v.y = res[(ii4 + 1) * 129 + cc];
    v.z = res[(ii4 + 2) * 129 + cc];
    v.w = res[(ii4 + 3) * 129 + cc];
    *(float4*)(out + ((size_t)(b * C_ + cc)) * N_ + i0 + ii4) = v;
  }
}

extern "C" void kernel_launch(void* const* d_in, const int* in_sizes, int n_in,
                              void* d_out, int out_size, void* d_ws, size_t ws_size,
                              hipStream_t stream) {
  (void)in_sizes; (void)n_in; (void)out_size; (void)ws_size;
  const float* x = (const float*)d_in[0];
  const float* W = (const float*)d_in[1];
  const float* a = (const float*)d_in[2];
  // d_in[3] (GL) is provably unused: adj > 0 everywhere.
  float* out = (float*)d_out;
  float* ws = (float*)d_ws;

  float* h    = ws + H_OFF;
  float* p    = ws + P_OFF;
  float* q    = ws + Q_OFF;
  float* q_s  = ws + QS_OFF;
  float* u_s  = ws + US_OFF;
  float* v_s  = ws + VS_OFF;
  int*   srt  = (int*)(ws + SRT_OFF);
  float* SUS  = ws + SUS_OFF;
  float* PVS  = ws + PVS_OFF;
  float* SUl  = ws + SUL_OFF;
  float* PVl  = ws + PVL_OFF;
  float* totU = ws + TOTU_OFF;
  float* totV = ws + TOTV_OFF;
  float* mrw  = ws + MR_OFF;
  float* mpart = ws + MPART_OFF;
  float* pthr = ws + PTHR_OFF;
  int*   ithr = (int*)(ws + ITHR_OFF);

  k_gemm<<<dim3((B_ * N_) / 64), dim3(256), 0, stream>>>(x, W, a, h, p, q, mpart);
  k_sort<<<dim3(3 * B_), dim3(256), 0, stream>>>(q, p, mpart, q_s, u_s, v_s, srt, SUS, PVS, pthr, ithr, mrw);
  k_scanA<<<dim3(B_ * NCH_), dim3(256), 0, stream>>>(h, u_s, v_s, srt, SUl, PVl, totU, totV);
  k_out<<<dim3(B_ * 32), dim3(256), 0, stream>>>(p, q_s, pthr, ithr, SUS, PVS, SUl, PVl, totU, totV, mrw, out);
}

// Round 12
// 111.098 us; speedup vs baseline: 1.0990x; 1.0990x over previous
//
#include <hip/hip_runtime.h>
#include <hip/hip_bf16.h>
#include <math.h>

// Problem constants (fixed by setup_inputs): B=8, N=2048, C=128, TOP_K=512
// Algebraic structure (verified passing since R1):
//  - adj = softmax(relu(GL GL^T)) + I > 0 everywhere  => att == e, GL unused.
//  - e[b,i,j] = leaky_relu(p_i + q_j) monotone in p_i => mask depends only on
//    (b,i): row kept iff (p_i, -i) >= 512th largest (p, -idx).
//  - Unselected rows: softmax(all-zeros) = uniform => relu(mean_j h[b,j,:]).
//  - Kept rows: exp(leaky_relu(p+q)) separates at q >= -p into e^p e^q and
//    e^{.01p} e^{.01q}; sort by q => suffix/prefix sums + bsearch per row.
//
// R1: k_mean 252us -> 2-stage. R2: k_rank 52.8us -> p-sort threshold.
// R3: u64-key sort + fused scans; 119.9. R4: REGRESSED 131 (gemm 512thr;
// k_out 108KB LDS). R5: REGRESSED 130.7. R6: REGRESSED 155.8 (per-block
// __threadfence = L2 writeback on multi-XCD; never per-block device fences).
// R7: R3 restore 120.2. R8: k_tab flatten + concurrent mean: 116.5.
// R9: gemm 4x8/thread + CL=64 tables-in-k_out, 4 launches: 111.2 <- BEST.
// R10: REGRESSED 122.1: 256thr x 8elem register sort. Re-attribution: R5's
//      +11 was the same sort (not k_prep). On a 16-block latency-critical
//      path, 8 elem/thread quadruples serial work per phase; barrier savings
//      (~1us) << serial-depth cost (~11us). Threads beat registers when the
//      machine is idle: distribute elements, eat the barriers.
// R11: exact R9/R10-best revert (1024-thr 2-elem sort). Measured 111.2.

#define B_ 8
#define N_ 2048
#define C_ 128
#define TOPK_ 512
#define NCH_ 32      // chunks per batch
#define CL_ 64       // chunk length (NCH_*CL_ == N_)
#define NP1_ 2050    // padded N+1 stride (even -> float2-aligned)

// ---------------- ws layout (floats) ----------------
#define H_OFF    ((size_t)0)
#define P_OFF    (H_OFF + (size_t)B_*N_*C_)
#define Q_OFF    (P_OFF + (size_t)B_*N_)
#define QS_OFF   (Q_OFF + (size_t)B_*N_)
#define US_OFF   (QS_OFF + (size_t)B_*N_)
#define VS_OFF   (US_OFF + (size_t)B_*N_)
#define SRT_OFF  (VS_OFF + (size_t)B_*N_)          // ints
#define SUS_OFF  (SRT_OFF + (size_t)B_*N_)         // B*NP1_
#define PVS_OFF  (SUS_OFF + (size_t)B_*NP1_)       // B*NP1_
#define SUL_OFF  (PVS_OFF + (size_t)B_*NP1_)
#define PVL_OFF  (SUL_OFF + (size_t)B_*N_*128)
#define TOTU_OFF (PVL_OFF + (size_t)B_*N_*128)
#define TOTV_OFF (TOTU_OFF + (size_t)B_*NCH_*128)
#define MR_OFF   (TOTV_OFF + (size_t)B_*NCH_*128)
#define MPART_OFF (MR_OFF + (size_t)B_*C_)         // B*32*128 tile col sums
#define PTHR_OFF (MPART_OFF + (size_t)B_*32*C_)    // B floats
#define ITHR_OFF (PTHR_OFF + (size_t)B_)           // B ints

// monotone float <-> sortable uint
__device__ __forceinline__ unsigned enc_f(float f) {
  unsigned b = __float_as_uint(f);
  return b ^ ((b >> 31) ? 0xFFFFFFFFu : 0x80000000u);
}
__device__ __forceinline__ float dec_f(unsigned e) {
  unsigned b = (e & 0x80000000u) ? (e ^ 0x80000000u) : ~e;
  return __uint_as_float(b);
}
__device__ __forceinline__ unsigned long long sxor64(unsigned long long v, int m) {
  int lo = __shfl_xor((int)(unsigned)(v & 0xffffffffULL), m, 64);
  int hi = __shfl_xor((int)(unsigned)(v >> 32), m, 64);
  return (((unsigned long long)(unsigned)hi) << 32) | (unsigned)lo;
}

// ---------------- K1: h = x@W (f32), p = h@a1, q = h@a2, mean partials ------
// 256 threads, 64 rows/block. Thread (cg=t&15, rp=t>>4) owns rows
// {4rp..4rp+3} x cols {4cg..4cg+3, 4cg+64..4cg+67}: 32 FMA per k-iter from
// 2 ds_read_b128 (W) + 4 ds_read_b32 (x) -> VALU-bound. <=2-way bank alias.
__global__ __launch_bounds__(256) void k_gemm(const float* __restrict__ x,
                                              const float* __restrict__ W,
                                              const float* __restrict__ a,
                                              float* __restrict__ h,
                                              float* __restrict__ p,
                                              float* __restrict__ q,
                                              float* __restrict__ mpart) {
  __shared__ float Wl[64 * 128];       // 32 KB
  __shared__ float xl[64 * 68];        // 17 KB (reused as 16x128 scratch)
  __shared__ float a1l[128], a2l[128];
  __shared__ float redp[64][16], redq[64][16];  // 8 KB
  const int t = threadIdx.x;
  const int r0 = blockIdx.x * 64;
  if (t < 128) { a1l[t] = a[t]; a2l[t] = a[128 + t]; }
  const int cg = t & 15, rp = t >> 4;
  float acc[4][8];
#pragma unroll
  for (int r = 0; r < 4; ++r)
#pragma unroll
    for (int j = 0; j < 8; ++j) acc[r][j] = 0.f;

  for (int kc = 0; kc < 2; ++kc) {
    __syncthreads();
    const float4* W4 = (const float4*)(W + (size_t)kc * 64 * 128);
    float4* Wl4 = (float4*)Wl;
#pragma unroll
    for (int i = 0; i < 8; ++i) Wl4[t + 256 * i] = W4[t + 256 * i];
#pragma unroll
    for (int i = 0; i < 4; ++i) {
      int idx = t + 256 * i;
      int row = idx >> 4, c4i = idx & 15;
      float4 v = *(const float4*)(x + (size_t)(r0 + row) * 128 + kc * 64 + c4i * 4);
      ((float4*)xl)[row * 17 + c4i] = v;
    }
    __syncthreads();
    for (int k = 0; k < 64; ++k) {
      const float4* Wr = (const float4*)(Wl + k * 128);
      float4 w0 = Wr[cg];
      float4 w1 = Wr[cg + 16];
#pragma unroll
      for (int r = 0; r < 4; ++r) {
        float xv = xl[(4 * rp + r) * 68 + k];
        acc[r][0] = fmaf(xv, w0.x, acc[r][0]);
        acc[r][1] = fmaf(xv, w0.y, acc[r][1]);
        acc[r][2] = fmaf(xv, w0.z, acc[r][2]);
        acc[r][3] = fmaf(xv, w0.w, acc[r][3]);
        acc[r][4] = fmaf(xv, w1.x, acc[r][4]);
        acc[r][5] = fmaf(xv, w1.y, acc[r][5]);
        acc[r][6] = fmaf(xv, w1.z, acc[r][6]);
        acc[r][7] = fmaf(xv, w1.w, acc[r][7]);
      }
    }
  }
  // epilogue: h stores + p/q partials + mean column partials
  const int c0 = 4 * cg, c1 = 4 * cg + 64;
  size_t hb = (size_t)r0 * 128;
  __syncthreads();               // xl reads done before scratch reuse
  float* scratch = xl;           // 16 x 128 four-row sums
#pragma unroll
  for (int r = 0; r < 4; ++r) {
    int row = 4 * rp + r;
    *(float4*)(h + hb + (size_t)row * 128 + c0) =
        make_float4(acc[r][0], acc[r][1], acc[r][2], acc[r][3]);
    *(float4*)(h + hb + (size_t)row * 128 + c1) =
        make_float4(acc[r][4], acc[r][5], acc[r][6], acc[r][7]);
    float pp = 0.f, qq = 0.f;
#pragma unroll
    for (int j = 0; j < 4; ++j) {
      pp = fmaf(acc[r][j], a1l[c0 + j], pp);
      qq = fmaf(acc[r][j], a2l[c0 + j], qq);
      pp = fmaf(acc[r][4 + j], a1l[c1 + j], pp);
      qq = fmaf(acc[r][4 + j], a2l[c1 + j], qq);
    }
    redp[row][cg] = pp; redq[row][cg] = qq;
  }
#pragma unroll
  for (int j = 0; j < 4; ++j) {
    scratch[rp * 128 + c0 + j] = acc[0][j] + acc[1][j] + acc[2][j] + acc[3][j];
    scratch[rp * 128 + c1 + j] = acc[0][4+j] + acc[1][4+j] + acc[2][4+j] + acc[3][4+j];
  }
  __syncthreads();
  if (t < 64) {
    float sp = 0.f, sq = 0.f;
#pragma unroll
    for (int i = 0; i < 16; ++i) { sp += redp[t][i]; sq += redq[t][i]; }
    p[r0 + t] = sp;
    q[r0 + t] = sq;
  }
  if (t < 128) {
    float s = 0.f;
#pragma unroll
    for (int rr = 0; rr < 16; ++rr) s += scratch[rr * 128 + t];
    mpart[(size_t)blockIdx.x * 128 + t] = s;
  }
}

// ---------------- K2: per-batch sorts + scalar scans + mean ----------------
// blocks 0..B_-1   : sort q[b] asc -> q_s/u_s/v_s/srt + SUS/PVS
// blocks B_..2B_-1 : sort p[b] desc -> pthr/ithr (rank 511)
// blocks 2B_..3B_-1: mrw[b] = relu(mean h cols) from mpart (concurrent, free)
__global__ __launch_bounds__(1024) void k_sort(const float* __restrict__ q,
                                               const float* __restrict__ p,
                                               const float* __restrict__ mpart,
                                               float* __restrict__ q_s,
                                               float* __restrict__ u_s,
                                               float* __restrict__ v_s,
                                               int* __restrict__ srt,
                                               float* __restrict__ SUS,
                                               float* __restrict__ PVS,
                                               float* __restrict__ pthr,
                                               int* __restrict__ ithr,
                                               float* __restrict__ mrw) {
  __shared__ unsigned long long sh[N_];   // 16 KB
  __shared__ float2 sa[1024], sb[1024];   // 16 KB (q-blocks only)
  __shared__ float red[8][128];           // 4 KB  (mean blocks only)
  const int blk = blockIdx.x, t = threadIdx.x;

  if (blk >= 2 * B_) {
    // ---- mean path ----
    const int b = blk - 2 * B_;
    const int c = t & 127, i = t >> 7;
    float s = 0.f;
#pragma unroll
    for (int j = 4 * i; j < 4 * i + 4; ++j)
      s += mpart[(size_t)(b * 32 + j) * 128 + c];
    red[i][c] = s;
    __syncthreads();
    if (t < 128) {
      float s2 = 0.f;
#pragma unroll
      for (int i2 = 0; i2 < 8; ++i2) s2 += red[i2][t];
      mrw[b * 128 + t] = fmaxf(s2 * (1.0f / (float)N_), 0.f);
    }
    return;
  }

  const bool isP = blk >= B_;
  const int b = isP ? blk - B_ : blk;
  const float* src = isP ? p : q;
  float2 f2 = *(const float2*)(src + b * N_ + 2 * t);
  unsigned k0 = enc_f(f2.x), k1 = enc_f(f2.y);
  if (isP) { k0 = ~k0; k1 = ~k1; }
  unsigned long long r0 = ((unsigned long long)k0 << 32) | (unsigned)(2 * t);
  unsigned long long r1 = ((unsigned long long)k1 << 32) | (unsigned)(2 * t + 1);

  for (int k = 2; k <= N_; k <<= 1) {
    const bool up = (((2 * t) & k) == 0);
    int j = k >> 1;
    for (; j >= 128; j >>= 1) {           // cross-wave: LDS
      *(ulonglong2*)(sh + 2 * t) = make_ulonglong2(r0, r1);
      __syncthreads();
      int pe = (2 * t) ^ j;               // j even -> pe even, 16B aligned
      ulonglong2 pp = *(const ulonglong2*)(sh + pe);
      bool lower = (((2 * t) & j) == 0);
      bool kmin = (up == lower);
      r0 = kmin ? (r0 < pp.x ? r0 : pp.x) : (r0 > pp.x ? r0 : pp.x);
      r1 = kmin ? (r1 < pp.y ? r1 : pp.y) : (r1 > pp.y ? r1 : pp.y);
      __syncthreads();
    }
    for (; j >= 2; j >>= 1) {             // within-wave: shuffles, no barrier
      int j2 = j >> 1;
      unsigned long long p0 = sxor64(r0, j2);
      unsigned long long p1 = sxor64(r1, j2);
      bool lower = ((t & j2) == 0);
      bool kmin = (up == lower);
      r0 = kmin ? (r0 < p0 ? r0 : p0) : (r0 > p0 ? r0 : p0);
      r1 = kmin ? (r1 < p1 ? r1 : p1) : (r1 > p1 ? r1 : p1);
    }
    // j == 1: thread-internal
    if (up) {
      if (r0 > r1) { unsigned long long tm = r0; r0 = r1; r1 = tm; }
    } else {
      if (r1 > r0) { unsigned long long tm = r0; r0 = r1; r1 = tm; }
    }
  }

  if (isP) {
    if (t == 255) {  // element 511 = 2*255+1
      unsigned key = (unsigned)(r1 >> 32);
      pthr[b] = dec_f(~key);
      ithr[b] = (int)(unsigned)(r1 & 0xffffffffULL);
    }
    return;
  }
  // q path: outputs + fused scalar scans
  float v0 = dec_f((unsigned)(r0 >> 32));
  float v1 = dec_f((unsigned)(r1 >> 32));
  int i0 = (int)(unsigned)(r0 & 0xffffffffULL);
  int i1 = (int)(unsigned)(r1 & 0xffffffffULL);
  float u0 = __expf(v0), u1 = __expf(v1);
  float w0 = __expf(0.01f * v0), w1 = __expf(0.01f * v1);
  *(float2*)(q_s + b * N_ + 2 * t) = make_float2(v0, v1);
  *(float2*)(u_s + b * N_ + 2 * t) = make_float2(u0, u1);
  *(float2*)(v_s + b * N_ + 2 * t) = make_float2(w0, w1);
  *(int2*)(srt + b * N_ + 2 * t) = make_int2(i0, i1);
  // combined scan: x = pair-u reversed (suffix), y = pair-w (prefix)
  float pu = u0 + u1, pw = w0 + w1;
  sa[1023 - t].x = pu;
  sa[t].y = pw;
  __syncthreads();
  float2* cur = sa; float2* nxt = sb;
  for (int off = 1; off < 1024; off <<= 1) {
    float2 vv = cur[t];
    if (t >= off) { float2 o = cur[t - off]; vv.x += o.x; vv.y += o.y; }
    nxt[t] = vv;
    __syncthreads();
    float2* tmp = cur; cur = nxt; nxt = tmp;
  }
  float PSt = cur[1023 - t].x;   // suffix-inclusive of pair-u from pair t
  float PPt = cur[t].y;          // prefix-inclusive of pair-w through pair t
  *(float2*)(SUS + (size_t)b * NP1_ + 2 * t) = make_float2(PSt, PSt - u0);
  *(float2*)(PVS + (size_t)b * NP1_ + 2 * t) = make_float2(PPt - pw, PPt - w1);
  if (t == 1023) {
    SUS[(size_t)b * NP1_ + N_] = 0.f;
    PVS[(size_t)b * NP1_ + N_] = PPt;
  }
}

// ---------------- K3: chunk-local suffix(u*h) / exclusive-prefix(w*h) --------
// 1 chunk of CL_=64 per 256-thread block (grid B*32 = 256 = full machine).
// Directions split: t<128 suffix scan (col t), t>=128 prefix scan (col t-128).
__global__ __launch_bounds__(256) void k_scanA(const float* __restrict__ h,
                                               const float* __restrict__ u_s,
                                               const float* __restrict__ v_s,
                                               const int* __restrict__ srt,
                                               float* __restrict__ SUl,
                                               float* __restrict__ PVl,
                                               float* __restrict__ totU,
                                               float* __restrict__ totV) {
  __shared__ float hl[CL_][128];   // 32 KB
  __shared__ float ul[CL_], vl[CL_];
  __shared__ int sl[CL_];
  const int b = blockIdx.x >> 5, ch = blockIdx.x & 31;
  const int t = threadIdx.x;
  const int base = b * N_ + ch * CL_;
  if (t < CL_) { ul[t] = u_s[base + t]; vl[t] = v_s[base + t]; sl[t] = srt[base + t]; }
  __syncthreads();
  // float4 gather: lane (c4 = t&31, rr = t>>5 in [0,8)) loads rows rr+8i
  {
    const int c4 = t & 31, rr = t >> 5;
#pragma unroll
    for (int i = 0; i < 8; ++i) {
      int tt = rr + 8 * i;
      float4 v = *(const float4*)(h + ((size_t)b * N_ + sl[tt]) * 128 + 4 * c4);
      *(float4*)(&hl[tt][4 * c4]) = v;
    }
  }
  __syncthreads();
  if (t < 128) {
    const int c = t;
    float run = 0.f;
    for (int tt = CL_ - 1; tt >= 0; --tt) {
      run = fmaf(ul[tt], hl[tt][c], run);
      SUl[((size_t)(base + tt)) * 128 + c] = run;
    }
    totU[(size_t)(b * NCH_ + ch) * 128 + c] = run;
  } else {
    const int c = t - 128;
    float run2 = 0.f;
    for (int tt = 0; tt < CL_; ++tt) {
      PVl[((size_t)(base + tt)) * 128 + c] = run2;
      run2 = fmaf(vl[tt], hl[tt][c], run2);
    }
    totV[(size_t)(b * NCH_ + ch) * 128 + c] = run2;
  }
}

// ---------------- K4: tables from totU/totV (LDS) + combine + store ---------
// Tables are 33x128x2 = 34 KB (NCH_=32) -> total ~76 KB LDS, 2 blocks/CU.
__global__ __launch_bounds__(256) void k_out(const float* __restrict__ p,
                                             const float* __restrict__ q_s,
                                             const float* __restrict__ pthr,
                                             const int* __restrict__ ithr,
                                             const float* __restrict__ SUS,
                                             const float* __restrict__ PVS,
                                             const float* __restrict__ SUl,
                                             const float* __restrict__ PVl,
                                             const float* __restrict__ totU,
                                             const float* __restrict__ totV,
                                             const float* __restrict__ mrw,
                                             float* __restrict__ out) {
  __shared__ float qs_l[N_];                 // 8 KB
  __shared__ float res[64 * 129];            // 33 KB
  __shared__ float CSUs[(NCH_ + 1) * 128];   // 16.9 KB
  __shared__ float CPVs[(NCH_ + 1) * 128];   // 16.9 KB
  __shared__ float mr[128];
  __shared__ float A_s[64], B_s[64], invD[64];
  __shared__ int lo_s[64], keep_s[64];
  const int b = blockIdx.x >> 5, tile = blockIdx.x & 31;
  const int t = threadIdx.x;
  const int i0 = tile * 64;
  for (int i = t; i < N_; i += 256) qs_l[i] = q_s[b * N_ + i];
  if (t < 128) {
    mr[t] = mrw[b * 128 + t];
    float s = 0.f;
    CSUs[NCH_ * 128 + t] = 0.f;
    for (int cc = NCH_ - 1; cc >= 0; --cc) {
      s += totU[(size_t)(b * NCH_ + cc) * 128 + t];
      CSUs[cc * 128 + t] = s;
    }
  } else {
    const int c2 = t - 128;
    float s2 = 0.f;
    for (int cc = 0; cc < NCH_; ++cc) {
      CPVs[cc * 128 + c2] = s2;
      s2 += totV[(size_t)(b * NCH_ + cc) * 128 + c2];
    }
    CPVs[NCH_ * 128 + c2] = s2;
  }
  __syncthreads();
  if (t < 64) {  // parallel bsearch + per-row scalars
    float pv = p[b * N_ + i0 + t];
    float thrv = pthr[b]; int thri = ithr[b];
    bool keep = (pv > thrv) || (pv == thrv && (i0 + t) <= thri);
    keep_s[t] = keep ? 1 : 0;
    float thr = -pv;
    int lo = 0, hi = N_;
    while (lo < hi) { int mid = (lo + hi) >> 1; if (qs_l[mid] < thr) lo = mid + 1; else hi = mid; }
    lo_s[t] = lo;
    float A = __expf(pv), Bv = __expf(0.01f * pv);
    A_s[t] = A; B_s[t] = Bv;
    float sus = SUS[(size_t)b * NP1_ + lo];
    float pvs = PVS[(size_t)b * NP1_ + lo];
    invD[t] = 1.0f / fmaf(A, sus, Bv * pvs);
  }
  __syncthreads();
  const int half = t >> 7, c = t & 127;
#pragma unroll 4
  for (int ii2 = 0; ii2 < 64; ii2 += 2) {
    int ii = ii2 + half;
    float outv;
    if (keep_s[ii]) {
      int lo = lo_s[ii];
      float A = A_s[ii], Bv = B_s[ii];
      float suc, pvc;
      if (lo < N_) {
        int chn = lo >> 6;   // / CL_
        size_t ro = ((size_t)(b * N_ + lo)) * 128;
        suc = SUl[ro + c] + CSUs[(chn + 1) * 128 + c];
        pvc = PVl[ro + c] + CPVs[chn * 128 + c];
      } else {
        suc = 0.f;
        pvc = CPVs[NCH_ * 128 + c];
      }
      outv = fmaxf(fmaf(A, suc, Bv * pvc) * invD[ii], 0.f);
    } else {
      outv = mr[c];
    }
    res[ii * 129 + c] = outv;
  }
  __syncthreads();
  // out[b][c][i] = res[i - i0][c]
#pragma unroll
  for (int pass = 0; pass < 8; ++pass) {
    int cc = (t >> 4) + pass * 16;
    int ii4 = (t & 15) * 4;
    float4 v;
    v.x = res[(ii4 + 0) * 129 + cc];
    v.y = res[(ii4 + 1) * 129 + cc];
    v.z = res[(ii4 + 2) * 129 + cc];
    v.w = res[(ii4 + 3) * 129 + cc];
    *(float4*)(out + ((size_t)(b * C_ + cc)) * N_ + i0 + ii4) = v;
  }
}

extern "C" void kernel_launch(void* const* d_in, const int* in_sizes, int n_in,
                              void* d_out, int out_size, void* d_ws, size_t ws_size,
                              hipStream_t stream) {
  (void)in_sizes; (void)n_in; (void)out_size; (void)ws_size;
  const float* x = (const float*)d_in[0];
  const float* W = (const float*)d_in[1];
  const float* a = (const float*)d_in[2];
  // d_in[3] (GL) is provably unused: adj > 0 everywhere.
  float* out = (float*)d_out;
  float* ws = (float*)d_ws;

  float* h    = ws + H_OFF;
  float* p    = ws + P_OFF;
  float* q    = ws + Q_OFF;
  float* q_s  = ws + QS_OFF;
  float* u_s  = ws + US_OFF;
  float* v_s  = ws + VS_OFF;
  int*   srt  = (int*)(ws + SRT_OFF);
  float* SUS  = ws + SUS_OFF;
  float* PVS  = ws + PVS_OFF;
  float* SUl  = ws + SUL_OFF;
  float* PVl  = ws + PVL_OFF;
  float* totU = ws + TOTU_OFF;
  float* totV = ws + TOTV_OFF;
  float* mrw  = ws + MR_OFF;
  float* mpart = ws + MPART_OFF;
  float* pthr = ws + PTHR_OFF;
  int*   ithr = (int*)(ws + ITHR_OFF);

  k_gemm<<<dim3((B_ * N_) / 64), dim3(256), 0, stream>>>(x, W, a, h, p, q, mpart);
  k_sort<<<dim3(3 * B_), dim3(1024), 0, stream>>>(q, p, mpart, q_s, u_s, v_s, srt, SUS, PVS, pthr, ithr, mrw);
  k_scanA<<<dim3(B_ * NCH_), dim3(256), 0, stream>>>(h, u_s, v_s, srt, SUl, PVl, totU, totV);
  k_out<<<dim3(B_ * 32), dim3(256), 0, stream>>>(p, q_s, pthr, ithr, SUS, PVS, SUl, PVl, totU, totV, mrw, out);
}